// Round 8
// baseline (713.233 us; speedup 1.0000x reference)
//
#include <hip/hip_runtime.h>
#include <math.h>

#define BATCH 32
#define NN 1024
#define MM 1024
#define RR 4                    // rows per lane
#define CC 4                    // cols per superstep
#define LANES 64
#define NWAVE 4
#define TPB (MM / 4)            // tile-columns per lane (256)
#define NSUP (TPB + LANES - 1)  // 319 lane-63 last superstep index is NSUP-1
#define LAG 72                  // wave lag: 63 lane skew + 9 margin
#define TOT (TPB + LANES - 1 + (NWAVE - 1) * LAG)   // 535
#define DEPTH 32                // LDS boundary ring depth (float4 entries)
#define DEC_WORDS_PER_BATCH ((NN / 4) * (MM / 4))     // 65536
#define DEC_BYTES ((size_t)BATCH * DEC_WORDS_PER_BATCH * 4)   // 8 MB
#define REQ_WS DEC_BYTES
#define LPATH (NN + MM - 1)     // 2047

__global__ void init_kernel(float* out) { out[0] = 0.0f; }

// ---- Backtrack word-walk (4x4 tile words, 3-candidate prefetch) -------------
__device__ inline void bt_walk4(const unsigned* __restrict__ sdec, int roff,
                                int iLow, int& i, int& j, int& n,
                                unsigned* __restrict__ path)
{
    int ri = i >> 2, jc = j >> 2;
    unsigned w = sdec[(ri - roff) * 256 + jc];
    while (true) {
        const int base = (ri - roff) * 256 + jc;
        const unsigned wl = sdec[(jc > 0)    ? base - 1   : base];
        const unsigned wu = sdec[(ri > roff) ? base - 256 : base];
        const unsigned wd = sdec[(ri > roff && jc > 0) ? base - 257 : base];
        bool done = false, susp = false;
        while (true) {
            path[n++] = ((unsigned)i << 16) | (unsigned)j;
            if ((i | j) == 0) { done = true; break; }
            const unsigned m = (w >> (((i & 3) * 4 + (j & 3)) * 2)) & 3u;
            i -= (m != 2u); j -= (m != 1u);
            if (i < iLow) { susp = true; break; }
            if ((i >> 2) != ri || (j >> 2) != jc) break;
        }
        if (done || susp) break;
        const int nri = i >> 2, njc = j >> 2;
        w = (nri == ri) ? wl : ((njc == jc) ? wu : wd);
        ri = nri; jc = njc;
    }
}

// ---- Fused DP + backtrack: 32 blocks (one per batch) x 256 threads ----------
// Wave w owns rows [256w,256w+256); lane l owns rows i0=256w+4l..i0+3 and at
// local superstep ul processes cols j0=4(ul-l)..j0+3. Intra-wave boundary via
// __shfl_up (result consumed next iteration - latency hidden by loop slack).
// Cross-wave boundary via 32-deep LDS float4 ring + per-wave-pair LDS seqlock:
// producer release-publishes progress every 8 supersteps (workgroup scope =
// lgkmcnt only, NO vmcnt drain); consumer acquire-gates its prefetch on a
// cached counter. NO __syncthreads in the DP loop - dec stores drain lazily.
// Decisions: one u32 per 4x4 tile, bit ((i&3)*4+(j&3))*2, dec[b][i>>2][j>>2].
__global__ __launch_bounds__(256, 1) void dtw_fused(
    const float* __restrict__ preds, const float* __restrict__ targs,
    const float* __restrict__ subcoef, unsigned* __restrict__ dec,
    float* __restrict__ out)
{
    const int b = blockIdx.x, t = threadIdx.x;
    const int l = t & 63, w = t >> 6;
    const float INF = __builtin_inff();

    __shared__ float pxA[NN], pyA[NN], txA[MM], tyA[MM];   // 16 KB
    __shared__ float ring[NWAVE - 1][DEPTH * 4];           // 1.5 KB
    __shared__ int prog[NWAVE - 1];
    __shared__ unsigned sdec[128 * 256];                   // 128 KB
    __shared__ unsigned path[LPATH + 1];                   // 8 KB
    __shared__ int sI, sJ, sN;
    __shared__ float wsum[NWAVE];

    for (int it = 0; it < NN / 256; ++it) {
        const int idx = it * 256 + t;
        const float4 p4 = ((const float4*)preds)[(size_t)b * NN + idx];
        pxA[idx] = p4.x; pyA[idx] = p4.y;
        const float4 t4 = ((const float4*)targs)[(size_t)b * MM + idx];
        txA[idx] = t4.x; tyA[idx] = t4.y;
    }
    if (t < NWAVE - 1) prog[t] = 0;
    __syncthreads();

    // ---------------- DP ----------------
    const int i0 = (w << 8) + (l << 2);
    const float4 px4 = ((const float4*)pxA)[i0 >> 2];
    const float4 py4 = ((const float4*)pyA)[i0 >> 2];
    const float px[RR] = {px4.x, px4.y, px4.z, px4.w};
    const float py[RR] = {py4.x, py4.y, py4.z, py4.w};
    unsigned* __restrict__ decT =
        dec + (size_t)b * DEC_WORDS_PER_BATCH + (size_t)(i0 >> 2) * TPB;

    float Dp[RR], Dbot[CC], bv[CC];
    #pragma unroll
    for (int r = 0; r < RR; ++r) Dp[r] = INF;
    #pragma unroll
    for (int c = 0; c < CC; ++c) { Dbot[c] = INF; bv[c] = INF; }
    // dg for (i0,j0) = previous superstep's bv[3]. Seed: dg=0 at global (0,0)
    // reproduces the reference's inf->0 substitution exactly (argmin=0 too).
    float bndRet = (w == 0 && l == 0) ? 0.0f : INF;
    float4 tx4 = ((const float4*)txA)[0], ty4 = ((const float4*)tyA)[0];
    float rv0 = INF, rv1 = INF, rv2 = INF, rv3 = INF;   // ring prefetch
    int cachedProg = 0;

    for (int u = 0; u < TOT; ++u) {
        const int ul = u - LAG * w;          // local superstep
        const int un = ul + 1;
        const bool act = (ul >= l) && (ul < l + TPB);
        if (act) {
            const float cx[CC] = {tx4.x, tx4.y, tx4.z, tx4.w};
            const float cy[CC] = {ty4.x, ty4.y, ty4.z, ty4.w};
            float cost[RR][CC];
            #pragma unroll
            for (int c = 0; c < CC; ++c)
                #pragma unroll
                for (int r = 0; r < RR; ++r) {
                    const float dx = px[r] - cx[c], dy = py[r] - cy[c];
                    cost[r][c] = __builtin_amdgcn_sqrtf(dx * dx + dy * dy);
                }
            unsigned word = 0;
            #pragma unroll
            for (int c = 0; c < CC; ++c) {
                float up = bv[c];                   // D[i0-1][j0+c]
                float dg = (c == 0) ? bndRet : bv[c - 1];
                #pragma unroll
                for (int r = 0; r < RR; ++r) {
                    const float lf = Dp[r];         // D[i0+r][j0+c-1]
                    const float best = fminf(dg, fminf(up, lf));
                    // == JAX argmin([dg,up,lf]) first-min tie order (R6-proven)
                    const unsigned m = (best == dg) ? 0u
                                     : ((best == up) ? 1u : 2u);
                    const float D = cost[r][c] + best;
                    word |= m << ((r * 4 + c) * 2);
                    dg = lf; up = D; Dp[r] = D;
                }
                Dbot[c] = up;
            }
            decT[ul - l] = word;                    // fire-and-forget
            if (l == LANES - 1 && w < NWAVE - 1) {  // publish bottom row
                volatile float* rp = &ring[w][(ul & (DEPTH - 1)) * 4];
                rp[0] = Dbot[0]; rp[1] = Dbot[1];
                rp[2] = Dbot[2]; rp[3] = Dbot[3];
                if ((ul & 7) == 7 || ul == NSUP - 1)
                    __hip_atomic_store(&prog[w], ul + 1, __ATOMIC_RELEASE,
                                       __HIP_MEMORY_SCOPE_WORKGROUP);
            }
        }
        // ---- uniform epilogue: retain dg, boundary pass, prefetch next ----
        bndRet = bv[CC - 1];
        #pragma unroll
        for (int c = 0; c < CC; ++c) bv[c] = __shfl_up(Dbot[c], 1);
        // lane-0 boundary for next superstep: gated ring prefetch (broadcast)
        if (w > 0) {
            const int need = un + 64;
            if (need >= 64 && need <= NSUP && cachedProg < need) {
                do {
                    __builtin_amdgcn_s_sleep(1);
                    cachedProg = __hip_atomic_load(&prog[w - 1],
                        __ATOMIC_ACQUIRE, __HIP_MEMORY_SCOPE_WORKGROUP);
                } while (cachedProg < need);
            }
            const volatile float* rp =
                &ring[w - 1][(((un + 63) & (DEPTH - 1))) * 4];
            rv0 = rp[0]; rv1 = rp[1]; rv2 = rp[2]; rv3 = rp[3];
        }
        const bool useRing = (w > 0) && (un >= 0) && (un < TPB);
        const float m0 = useRing ? rv0 : INF;
        const float m1 = useRing ? rv1 : INF;
        const float m2 = useRing ? rv2 : INF;
        const float m3 = useRing ? rv3 : INF;
        if (l == 0) { bv[0] = m0; bv[1] = m1; bv[2] = m2; bv[3] = m3; }
        // coord prefetch, unconditional (clamped)
        int jn = CC * (un - l);
        jn = jn < 0 ? 0 : (jn > MM - 4 ? MM - 4 : jn);
        tx4 = ((const float4*)txA)[jn >> 2];
        ty4 = ((const float4*)tyA)[jn >> 2];
    }

    __threadfence_block();
    __syncthreads();   // drains each wave's dec stores (vmcnt) + joins waves

    // ---------------- Backtrack (R5-proven) ----------------
    const unsigned* __restrict__ decB = dec + (size_t)b * DEC_WORDS_PER_BATCH;
    // Phase A: tile-rows 128..255 (rows 512..1023) — contiguous 128 KB copy.
    {
        uint4* s4 = (uint4*)sdec;
        const uint4* g4 = (const uint4*)(decB + 128 * 256);
        for (int k = t; k < 8192; k += 256) s4[k] = g4[k];
    }
    __syncthreads();
    if (t == 0) {
        int i = NN - 1, j = MM - 1, n = 0;
        bt_walk4(sdec, 128, 512, i, j, n, path);
        sI = i; sJ = j; sN = n;
    }
    __syncthreads();
    // Phase B: tile-rows 0..127.
    {
        uint4* s4 = (uint4*)sdec;
        const uint4* g4 = (const uint4*)decB;
        for (int k = t; k < 8192; k += 256) s4[k] = g4[k];
    }
    __syncthreads();
    if (t == 0) {
        int i = sI, j = sJ, n = sN;
        bt_walk4(sdec, 0, 0, i, j, n, path);
        sN = n;
    }
    __syncthreads();

    // ---------------- Parallel loss over the path ----------------
    const float sc0 = subcoef[0], sc1 = subcoef[1];
    const int n = sN;
    float acc = 0.0f;
    for (int p = t; p < n; p += 256) {
        const unsigned e = path[p];
        const int i = (int)(e >> 16), j = (int)(e & 0xffffu);
        acc += fabsf(pxA[i] - txA[j]) * sc0 + fabsf(pyA[i] - tyA[j]) * sc1;
    }
    #pragma unroll
    for (int o = 32; o > 0; o >>= 1) acc += __shfl_down(acc, o);
    if ((t & 63) == 0) wsum[t >> 6] = acc;
    __syncthreads();
    if (t == 0) atomicAdd(out, (wsum[0] + wsum[1]) + (wsum[2] + wsum[3]));
}

// ------------- Fallback (R1 kernel, only if ws too small) --------------------
__global__ __launch_bounds__(256) void dtw_fallback(
    const float* __restrict__ preds, const float* __restrict__ targs,
    const float* __restrict__ subcoef, unsigned* __restrict__ dec,
    float* __restrict__ out)
{
    const int b = blockIdx.x;
    const int t = threadIdx.x;
    const float INF = __builtin_inff();
    __shared__ float px[NN], py[NN];
    __shared__ float txy[2 * MM];
    __shared__ float bbuf[2][256];

    for (int it = 0; it < NN / 256; ++it) {
        const int idx = it * 256 + t;
        const float4 p4 = ((const float4*)preds)[(size_t)b * NN + idx];
        px[idx] = p4.x; py[idx] = p4.y;
        const float4 t4 = ((const float4*)targs)[(size_t)b * MM + idx];
        txy[2 * idx] = t4.x; txy[2 * idx + 1] = t4.y;
    }
    bbuf[0][t] = INF; bbuf[1][t] = INF;
    __syncthreads();

    float pxr[4], pyr[4], Dp[4];
    #pragma unroll
    for (int r = 0; r < 4; ++r) {
        pxr[r] = px[4 * t + r]; pyr[r] = py[4 * t + r]; Dp[r] = INF;
    }
    float dgB = (t == 0) ? 0.0f : INF;
    unsigned packed = 0;
    unsigned* decB = dec + (size_t)b * 65536;
    for (int s = 0; s < MM + 255; ++s) {
        const int j = s - t;
        const float upB = (t == 0) ? INF : bbuf[(s + 1) & 1][t - 1];
        if (j >= 0 && j < MM) {
            const float txj = txy[2 * j], tyj = txy[2 * j + 1];
            float up = upB, dg = dgB;
            unsigned mbits = 0;
            #pragma unroll
            for (int r = 0; r < 4; ++r) {
                const float dx = pxr[r] - txj, dy = pyr[r] - tyj;
                const float c = sqrtf(dx * dx + dy * dy);
                const float lf = Dp[r];
                const unsigned m = (dg <= up && dg <= lf) ? 0u
                                 : ((up <= lf) ? 1u : 2u);
                mbits |= m << (r * 8 + (j & 3) * 2);
                const float Dc = c + fminf(up, fminf(dg, lf));
                dg = lf; up = Dc; Dp[r] = Dc;
            }
            packed |= mbits;
            if ((j & 3) == 3) { decB[(unsigned)t * 256 + (j >> 2)] = packed; packed = 0; }
            bbuf[s & 1][t] = Dp[3];
        }
        dgB = upB;
        __syncthreads();
    }
    __threadfence_block();
    __syncthreads();
    if (t == 0) {
        const float sc0 = subcoef[0], sc1 = subcoef[1];
        int i = NN - 1, jj = MM - 1;
        float loss = 0.0f;
        int ti = i >> 2, tj = jj >> 2;
        unsigned wv = decB[ti * 256 + tj];
        while (true) {
            const int tjl = (tj > 0) ? tj - 1 : 0;
            const int til = (ti > 0) ? ti - 1 : 0;
            const unsigned wl = decB[ti * 256 + tjl];
            const unsigned wu = decB[til * 256 + tj];
            const unsigned wd = decB[til * 256 + tjl];
            bool done = false;
            while (true) {
                loss += fabsf(px[i] - txy[2 * jj]) * sc0
                      + fabsf(py[i] - txy[2 * jj + 1]) * sc1;
                if ((i | jj) == 0) { done = true; break; }
                const unsigned m = (wv >> (((i & 3) * 4 + (jj & 3)) * 2)) & 3u;
                i -= (m != 2u); jj -= (m != 1u);
                if ((i >> 2) != ti || (jj >> 2) != tj) break;
            }
            if (done) break;
            const int nti = i >> 2, ntj = jj >> 2;
            wv = (nti == ti) ? wl : ((ntj == tj) ? wu : wd);
            ti = nti; tj = ntj;
        }
        atomicAdd(out, loss);
    }
}

extern "C" void kernel_launch(void* const* d_in, const int* in_sizes, int n_in,
                              void* d_out, int out_size, void* d_ws, size_t ws_size,
                              hipStream_t stream) {
    const float* preds   = (const float*)d_in[0];
    const float* targs   = (const float*)d_in[1];
    const float* subcoef = (const float*)d_in[2];
    float* out = (float*)d_out;
    unsigned* dec = (unsigned*)d_ws;   // 8 MB

    init_kernel<<<1, 1, 0, stream>>>(out);
    if (ws_size >= REQ_WS) {
        dtw_fused<<<BATCH, 256, 0, stream>>>(preds, targs, subcoef, dec, out);
    } else {
        dtw_fallback<<<BATCH, 256, 0, stream>>>(preds, targs, subcoef, dec, out);
    }
}